// Round 26
// baseline (178.457 us; speedup 1.0000x reference)
//
#include <hip/hip_runtime.h>
#include <hip/hip_bf16.h>
#include <stdint.h>

typedef unsigned short u16;
typedef short bf16x8 __attribute__((ext_vector_type(8)));
typedef short bf16x4 __attribute__((ext_vector_type(4)));
typedef float f32x4 __attribute__((ext_vector_type(4)));

#define NN 384
#define DIMC 128
#define NPOS (NN*NN)
#define EPSV 1e-5f

__device__ __forceinline__ u16 f2b(float f){
  __hip_bfloat16 h = __float2bfloat16(f);
  union { __hip_bfloat16 h; u16 u; } v; v.h = h;
  return v.u;
}
__device__ __forceinline__ float b2f(u16 h){
  union { uint32_t u; float f; } v; v.u = ((uint32_t)h) << 16;
  return v.f;
}
__device__ __forceinline__ float sigm(float z){
  return __builtin_amdgcn_rcpf(1.0f + __expf(-z));
}
__device__ __forceinline__ void glds16(const u16* g, u16* l){
  __builtin_amdgcn_global_load_lds((const __attribute__((address_space(1))) void*)(g),
                                   (__attribute__((address_space(3))) void*)(l), 16, 0, 0);
}

// ---------------- kernel 0: fp32 -> bf16 weights, V/G pair-interleaved ----------------
__global__ void wconv_k(const float* __restrict__ s_l, const float* __restrict__ s_lg,
                        const float* __restrict__ s_r, const float* __restrict__ s_rg,
                        const float* __restrict__ s_o, const float* __restrict__ s_ow,
                        u16* __restrict__ dst){
  int bid = blockIdx.x;
  int m = bid >> 6;                       // 0..5
  int off = ((bid & 63) << 8) + threadIdx.x;
  float v;
  if (m < 4){
    int r = off >> 7, ch = off & 127;
    int a = ((m & 1) << 6) + (r >> 1);
    const float* src = (m < 2) ? ((r & 1) ? s_lg : s_l) : ((r & 1) ? s_rg : s_r);
    v = src[(a << 7) + ch];
  } else if (m == 4) v = s_o[off];
  else v = s_ow[off];
  dst[(m << 14) + off] = f2b(v);
}

// ---------------- kernel 1a: LayerNorm streamer -> xn_g[j][i][ch] bf16 ----------------
__global__ __launch_bounds__(256) void ln_k(
    const float* __restrict__ x, const float* __restrict__ nw, const float* __restrict__ nb,
    u16* __restrict__ xng)
{
  const int tid = threadIdx.x, lane = tid & 63, wid = tid >> 6;
  const int bid = blockIdx.x;
  const int c = bid % NN, r0 = (bid / NN) * 64;
  const int l15 = lane & 15, lg = lane >> 4;

  float4 w0 = *(const float4*)(nw + l15*8);
  float4 w1 = *(const float4*)(nw + l15*8 + 4);
  float4 bb0 = *(const float4*)(nb + l15*8);
  float4 bb1 = *(const float4*)(nb + l15*8 + 4);
  float4 v0[4], v1[4];
  #pragma unroll
  for (int it = 0; it < 4; ++it){
    int p = wid*16 + it*4 + lg;
    const float* xp = x + ((size_t)(r0 + p)*NN + c)*DIMC + l15*8;
    v0[it] = *(const float4*)xp;
    v1[it] = *(const float4*)(xp + 4);
  }
  #pragma unroll
  for (int it = 0; it < 4; ++it){
    int p = wid*16 + it*4 + lg;
    float s  = (v0[it].x+v0[it].y)+(v0[it].z+v0[it].w)+((v1[it].x+v1[it].y)+(v1[it].z+v1[it].w));
    float sq = v0[it].x*v0[it].x+v0[it].y*v0[it].y+v0[it].z*v0[it].z+v0[it].w*v0[it].w
             + v1[it].x*v1[it].x+v1[it].y*v1[it].y+v1[it].z*v1[it].z+v1[it].w*v1[it].w;
    #pragma unroll
    for (int o = 8; o; o >>= 1){ s += __shfl_xor(s, o); sq += __shfl_xor(sq, o); }
    float mean = s * (1.0f/128.0f);
    float var  = sq * (1.0f/128.0f) - mean*mean;
    float inv  = rsqrtf(var + EPSV);
    bf16x8 o8;
    o8[0] = (short)f2b((v0[it].x - mean)*inv*w0.x + bb0.x);
    o8[1] = (short)f2b((v0[it].y - mean)*inv*w0.y + bb0.y);
    o8[2] = (short)f2b((v0[it].z - mean)*inv*w0.z + bb0.z);
    o8[3] = (short)f2b((v0[it].w - mean)*inv*w0.w + bb0.w);
    o8[4] = (short)f2b((v1[it].x - mean)*inv*w1.x + bb1.x);
    o8[5] = (short)f2b((v1[it].y - mean)*inv*w1.y + bb1.y);
    o8[6] = (short)f2b((v1[it].z - mean)*inv*w1.z + bb1.z);
    o8[7] = (short)f2b((v1[it].w - mean)*inv*w1.w + bb1.w);
    *(bf16x8*)(xng + ((size_t)c*NN + r0 + p)*DIMC + l15*8) = o8;
  }
}

// ---------------- kernel 1b: projection GEMM, 128x128 tiles, K=128 single-stage ----------------
// grid 5760 = 8 XCD x 720 (bijective). B (xn tile) LDS-staged via XOR-swizzled glds16;
// A (weights, L2-hot) loaded as a 16-deep REGISTER burst after the barrier. LDS 34.8KB.
__global__ __launch_bounds__(256) void projB_k(const u16* __restrict__ xng, const u16* __restrict__ wb2,
    const float* __restrict__ left_b, const float* __restrict__ lgate_b,
    const float* __restrict__ right_b, const float* __restrict__ rgate_b,
    const float* __restrict__ ogate_b,
    u16* __restrict__ Lp, u16* __restrict__ Rp, u16* __restrict__ gate)
{
  __shared__ u16 lds[17408];          // 34816 B: B-stage [0,16384); t=4 transpose [128][136]
  u16* Bsl = lds;
  const int tid = threadIdx.x, lane = tid & 63, wid = tid >> 6;
  const int bid = blockIdx.x;
  const int xcd = bid & 7, idx = bid >> 3;
  const int g = xcd*720 + idx;
  const int nt = g / 5, t = g % 5;
  const int c = nt / 3, r0 = (nt % 3) * 128;
  const size_t posbase = (size_t)c*NN + r0;
  const int l15 = lane & 15, lg = lane >> 4;
  const int wm = wid >> 1, wn = wid & 1;
  const int kofs = lg * 8;

  const u16* Aw = wb2 + t*16384;
  const u16* Bx = xng + posbase*DIMC;
  #pragma unroll
  for (int it = 0; it < 8; ++it){
    int cidx = it*256 + tid;
    int row = cidx >> 4, sl = cidx & 15;
    int so = row*128 + ((sl ^ (row & 15)) * 8);
    glds16(Bx + so, Bsl + cidx*8);
  }
  asm volatile("s_waitcnt vmcnt(0)" ::: "memory");
  __syncthreads();

  // A register burst: 16 independent 16B loads (L2-hot weights)
  bf16x8 areg[4][4];
  #pragma unroll
  for (int ks = 0; ks < 4; ++ks)
    #pragma unroll
    for (int m = 0; m < 4; ++m)
      areg[ks][m] = *(const bf16x8*)(Aw + (wm*64 + m*16 + l15)*128 + ks*32 + kofs);

  f32x4 acc[4][4];
  #pragma unroll
  for (int m = 0; m < 4; ++m)
    #pragma unroll
    for (int n = 0; n < 4; ++n) acc[m][n] = {0.f,0.f,0.f,0.f};

  #pragma unroll
  for (int ks = 0; ks < 4; ++ks){
    int sl = ((ks*4 + lg) ^ l15) * 8;
    bf16x8 bfr[4];
    #pragma unroll
    for (int n = 0; n < 4; ++n)
      bfr[n] = *(const bf16x8*)(Bsl + (wn*64 + n*16 + l15)*128 + sl);
    #pragma unroll
    for (int m = 0; m < 4; ++m)
      #pragma unroll
      for (int n = 0; n < 4; ++n)
        acc[m][n] = __builtin_amdgcn_mfma_f32_16x16x32_bf16(areg[ks][m], bfr[n], acc[m][n], 0, 0, 0);
  }

  if (t < 4){
    u16* dst = (t < 2) ? Lp : Rp;
    const float* bV = (t < 2) ? left_b : right_b;
    const float* bG = (t < 2) ? lgate_b : rgate_b;
    const int th = t & 1;
    #pragma unroll
    for (int m = 0; m < 4; ++m){
      int e0 = th*64 + wm*32 + m*8 + lg*2;
      float2 bv2 = *(const float2*)(bV + e0);
      float2 bg2 = *(const float2*)(bG + e0);
      #pragma unroll
      for (int n = 0; n < 4; ++n){
        size_t pp = posbase + wn*64 + n*16 + l15;
        float o0 = (acc[m][n][0] + bv2.x) * sigm(acc[m][n][1] + bg2.x);
        float o1 = (acc[m][n][2] + bv2.y) * sigm(acc[m][n][3] + bg2.y);
        dst[(size_t)e0*NPOS + pp]     = f2b(o0);
        dst[(size_t)(e0+1)*NPOS + pp] = f2b(o1);
      }
    }
  } else {
    __syncthreads();   // all waves done reading B -> reuse lds as [128 pos][136] transpose buf
    // column permutation: e = wm*64 + m*16 + lg*4 + r  ->  pi(e) = (lg*4+r)*8 + wm*4 + m
    #pragma unroll
    for (int m = 0; m < 4; ++m){
      int e = wm*64 + m*16 + lg*4;
      float4 bo4 = *(const float4*)(ogate_b + e);
      int colbase = (lg*4)*8 + wm*4 + m;
      #pragma unroll
      for (int n = 0; n < 4; ++n){
        int pl = wn*64 + n*16 + l15;
        lds[pl*136 + colbase     ] = f2b(sigm(acc[m][n][0] + bo4.x));
        lds[pl*136 + colbase +  8] = f2b(sigm(acc[m][n][1] + bo4.y));
        lds[pl*136 + colbase + 16] = f2b(sigm(acc[m][n][2] + bo4.z));
        lds[pl*136 + colbase + 24] = f2b(sigm(acc[m][n][3] + bo4.w));
      }
    }
    __syncthreads();
    #pragma unroll
    for (int it = 0; it < 8; ++it){
      int cidx = it*256 + tid;
      int row = cidx >> 4, s = cidx & 15;
      *(bf16x8*)(gate + ((size_t)(r0 + row)*NN + c)*DIMC + s*8) = *(const bf16x8*)(lds + row*136 + s*8);
    }
  }
}

// ---------------- kernel 2: triangle einsum -> outp[i][d][j] ----------------
__global__ __launch_bounds__(256) void phase2_k(const u16* __restrict__ Rp, const u16* __restrict__ Lp,
                                                u16* __restrict__ outp){
  __shared__ u16 lds[17408];
  u16* At = lds;
  u16* Bt = lds + 8192;
  const int tid = threadIdx.x, lane = tid & 63, wid = tid >> 6;
  const int bid = blockIdx.x;
  const int xcd = bid & 7, kk = bid >> 3;
  const int d = xcd*16 + kk/9, tile = kk % 9;
  const int i0 = (tile/3)*128, j0 = (tile%3)*128;
  const int wm = wid >> 1, wn = wid & 1;
  const int iw = wm*64, jw = wn*64;
  const int l15 = lane & 15, lg = lane >> 4;
  const int rmask = l15 & 7;

  int srcoff[4];
  #pragma unroll
  for (int cc = 0; cc < 4; ++cc){
    int idx = wid*256 + cc*64 + lane;
    int row = idx >> 3, slot = idx & 7;
    srcoff[cc] = row*NN + ((slot ^ (row & 7)) * 8);
  }

  f32x4 acc[4][4];
  #pragma unroll
  for (int m = 0; m < 4; ++m)
    #pragma unroll
    for (int n = 0; n < 4; ++n) acc[m][n] = {0.f,0.f,0.f,0.f};

  const u16* Rt0 = Rp + (size_t)d*NPOS + (size_t)i0*NN;
  const u16* Lt0 = Lp + (size_t)d*NPOS + (size_t)j0*NN;

  for (int k0 = 0; k0 < NN; k0 += 64){
    __syncthreads();
    #pragma unroll
    for (int cc = 0; cc < 4; ++cc){
      glds16(Rt0 + k0 + srcoff[cc], At + (wid*4 + cc)*512);
      glds16(Lt0 + k0 + srcoff[cc], Bt + (wid*4 + cc)*512);
    }
    asm volatile("s_waitcnt vmcnt(0)" ::: "memory");
    __syncthreads();
    #pragma unroll
    for (int ks = 0; ks < 2; ++ks){
      int sl = ((ks*4 + lg) ^ rmask) * 8;
      bf16x8 af[4], bfr[4];
      #pragma unroll
      for (int m = 0; m < 4; ++m)
        af[m] = *(const bf16x8*)(At + (iw + m*16 + l15)*64 + sl);
      #pragma unroll
      for (int n = 0; n < 4; ++n)
        bfr[n] = *(const bf16x8*)(Bt + (jw + n*16 + l15)*64 + sl);
      #pragma unroll
      for (int m = 0; m < 4; ++m)
        #pragma unroll
        for (int n = 0; n < 4; ++n)
          acc[m][n] = __builtin_amdgcn_mfma_f32_16x16x32_bf16(af[m], bfr[n], acc[m][n], 0, 0, 0);
    }
  }

  __syncthreads();
  #pragma unroll
  for (int m = 0; m < 4; ++m)
    #pragma unroll
    for (int n = 0; n < 4; ++n)
      #pragma unroll
      for (int r = 0; r < 4; ++r)
        lds[(iw + m*16 + lg*4 + r)*136 + jw + n*16 + l15] = f2b(acc[m][n][r]);
  __syncthreads();
  #pragma unroll
  for (int it = 0; it < 8; ++it){
    int idx = tid + it*256;
    int il = idx >> 4, s = idx & 15;
    *(bf16x8*)(outp + ((size_t)(i0 + il)*DIMC + d)*NN + j0 + s*8) = *(const bf16x8*)(lds + il*136 + s*8);
  }
}

// ---------------- kernel 3: LN + out-projection + gate (vectorized outp loads) ----------------
__global__ __launch_bounds__(256) void phase3_k(const u16* __restrict__ outp,
    const float* __restrict__ tonw, const float* __restrict__ tonb,
    const u16* __restrict__ wOut, const float* __restrict__ out_b,
    const u16* __restrict__ gate, float* __restrict__ out)
{
  __shared__ __align__(16) char shbuf[64*132*2];   // sred[32][64]+sqred[32][64] then xn2[64][132]
  float (*sred)[64]  = (float(*)[64])shbuf;
  float (*sqred)[64] = (float(*)[64])(shbuf + 8192);
  u16* xn2 = (u16*)shbuf;
  __shared__ float marr[64], iarr[64];
  const int tid = threadIdx.x, lane = tid & 63, wid = tid >> 6;
  const int bid = blockIdx.x;
  const int i = bid % NN, j0 = (bid / NN) * 64;
  const int l15 = lane & 15, lg = lane >> 4;

  const int jg = tid & 7;
  const int hg = tid >> 3;        // 0..31
  const int hb = hg * 4;
  const u16* lbase = outp + ((size_t)i*DIMC + hb)*NN + j0 + jg*8;
  bf16x8 v8[4];
  #pragma unroll
  for (int q = 0; q < 4; ++q) v8[q] = *(const bf16x8*)(lbase + (size_t)q*NN);

  float ps[8], psq[8];
  #pragma unroll
  for (int k = 0; k < 8; ++k){ ps[k] = 0.f; psq[k] = 0.f; }
  #pragma unroll
  for (int q = 0; q < 4; ++q)
    #pragma unroll
    for (int k = 0; k < 8; ++k){
      float v = b2f((u16)v8[q][k]);
      ps[k] += v; psq[k] += v*v;
    }
  {
    float4 a = {ps[0],ps[1],ps[2],ps[3]}, b = {ps[4],ps[5],ps[6],ps[7]};
    float4 c = {psq[0],psq[1],psq[2],psq[3]}, d = {psq[4],psq[5],psq[6],psq[7]};
    *(float4*)&sred[hg][jg*8]      = a;
    *(float4*)&sred[hg][jg*8 + 4]  = b;
    *(float4*)&sqred[hg][jg*8]     = c;
    *(float4*)&sqred[hg][jg*8 + 4] = d;
  }
  __syncthreads();
  if (tid < 64){
    float ts = 0.f, tq = 0.f;
    #pragma unroll
    for (int g2 = 0; g2 < 32; ++g2){ ts += sred[g2][tid]; tq += sqred[g2][tid]; }
    float mn  = ts * (1.f/128.f);
    float var = tq * (1.f/128.f) - mn*mn;
    marr[tid] = mn; iarr[tid] = rsqrtf(var + EPSV);
  }
  __syncthreads();

  {
    float mm[8], ii[8];
    #pragma unroll
    for (int k = 0; k < 8; ++k){ mm[k] = marr[jg*8 + k]; ii[k] = iarr[jg*8 + k]; }
    float4 tw = *(const float4*)(tonw + hb);
    float4 tb = *(const float4*)(tonb + hb);
    #pragma unroll
    for (int q = 0; q < 4; ++q){
      float w = q==0?tw.x : q==1?tw.y : q==2?tw.z : tw.w;
      float b = q==0?tb.x : q==1?tb.y : q==2?tb.z : tb.w;
      int h = hb + q;
      #pragma unroll
      for (int k = 0; k < 8; ++k){
        float v = b2f((u16)v8[q][k]);
        xn2[(jg*8 + k)*132 + h] = f2b((v - mm[k])*ii[k]*w + b);
      }
    }
  }
  __syncthreads();

  f32x4 acc[8];
  #pragma unroll
  for (int n = 0; n < 8; ++n) acc[n] = {0.f,0.f,0.f,0.f};
  const int row = wid*16 + l15;
  const int kofs = lg * 8;
  #pragma unroll
  for (int ks = 0; ks < 4; ++ks){
    const u16* ap = xn2 + row*132 + ks*32 + kofs;
    bf16x4 a0 = *(const bf16x4*)ap;
    bf16x4 a1 = *(const bf16x4*)(ap + 4);
    bf16x8 af = __builtin_shufflevector(a0, a1, 0,1,2,3,4,5,6,7);
    #pragma unroll
    for (int n = 0; n < 8; ++n){
      bf16x8 bm = *(const bf16x8*)(wOut + (n*16 + l15)*128 + ks*32 + kofs);
      acc[n] = __builtin_amdgcn_mfma_f32_16x16x32_bf16(af, bm, acc[n], 0, 0, 0);
    }
  }
  #pragma unroll
  for (int r = 0; r < 4; ++r){
    int p = wid*16 + lg*4 + r;
    bf16x8 g8 = *(const bf16x8*)(gate + ((size_t)i*NN + j0 + p)*DIMC + l15*8);
    #pragma unroll
    for (int n = 0; n < 8; ++n){
      int dd = n*16 + l15;
      size_t base = ((size_t)i*NN + j0 + p)*DIMC + dd;
      out[base] = (acc[n][r] + out_b[dd]) * b2f((u16)g8[n]);
    }
  }
}

extern "C" void kernel_launch(void* const* d_in, const int* in_sizes, int n_in,
                              void* d_out, int out_size, void* d_ws, size_t ws_size,
                              hipStream_t stream){
  const float* x       = (const float*)d_in[0];
  const float* norm_w  = (const float*)d_in[1];
  const float* norm_b  = (const float*)d_in[2];
  const float* left_w  = (const float*)d_in[3];
  const float* left_b  = (const float*)d_in[4];
  const float* right_w = (const float*)d_in[5];
  const float* right_b = (const float*)d_in[6];
  const float* lgate_w = (const float*)d_in[7];
  const float* lgate_b = (const float*)d_in[8];
  const float* rgate_w = (const float*)d_in[9];
  const float* rgate_b = (const float*)d_in[10];
  const float* ogate_w = (const float*)d_in[11];
  const float* ogate_b = (const float*)d_in[12];
  const float* ton_w   = (const float*)d_in[13];
  const float* ton_b   = (const float*)d_in[14];
  const float* out_w   = (const float*)d_in[15];
  const float* out_b   = (const float*)d_in[16];

  char* ws = (char*)d_ws;
  const size_t SZ = (size_t)NPOS * DIMC * sizeof(u16);
  u16* Lp   = (u16*)(ws);
  u16* Rp   = (u16*)(ws + SZ);
  u16* gate = (u16*)(ws + 2*SZ);
  u16* outp = (u16*)(ws + 3*SZ);
  u16* wb   = (u16*)(ws + 4*SZ);
  u16* xng  = outp;   // xn_g aliases outp: fully consumed by projB before phase2 writes outp

  wconv_k<<<dim3(384), dim3(256), 0, stream>>>(left_w, lgate_w, right_w, rgate_w, ogate_w, out_w, wb);
  ln_k<<<dim3(2304), dim3(256), 0, stream>>>(x, norm_w, norm_b, xng);
  projB_k<<<dim3(5760), dim3(256), 0, stream>>>(xng, wb,
      left_b, lgate_b, right_b, rgate_b, ogate_b, Lp, Rp, gate);
  phase2_k<<<dim3(1152), dim3(256), 0, stream>>>(Rp, Lp, outp);
  phase3_k<<<dim3(2304), dim3(256), 0, stream>>>(outp, ton_w, ton_b, wb + 5*16384, out_b, gate, (float*)d_out);
}

// Round 27
// 157.206 us; speedup vs baseline: 1.1352x; 1.1352x over previous
//
#include <hip/hip_runtime.h>
#include <hip/hip_bf16.h>
#include <stdint.h>

typedef unsigned short u16;
typedef short bf16x8 __attribute__((ext_vector_type(8)));
typedef short bf16x4 __attribute__((ext_vector_type(4)));
typedef float f32x4 __attribute__((ext_vector_type(4)));

#define NN 384
#define DIMC 128
#define NPOS (NN*NN)
#define EPSV 1e-5f

__device__ __forceinline__ u16 f2b(float f){
  __hip_bfloat16 h = __float2bfloat16(f);
  union { __hip_bfloat16 h; u16 u; } v; v.h = h;
  return v.u;
}
__device__ __forceinline__ float b2f(u16 h){
  union { uint32_t u; float f; } v; v.u = ((uint32_t)h) << 16;
  return v.f;
}
__device__ __forceinline__ float sigm(float z){
  return __builtin_amdgcn_rcpf(1.0f + __expf(-z));
}
__device__ __forceinline__ void glds16(const u16* g, u16* l){
  __builtin_amdgcn_global_load_lds((const __attribute__((address_space(1))) void*)(g),
                                   (__attribute__((address_space(3))) void*)(l), 16, 0, 0);
}

// ---------------- kernel 0: fp32 -> bf16 weights, V/G pair-interleaved ----------------
__global__ void wconv_k(const float* __restrict__ s_l, const float* __restrict__ s_lg,
                        const float* __restrict__ s_r, const float* __restrict__ s_rg,
                        const float* __restrict__ s_o, const float* __restrict__ s_ow,
                        u16* __restrict__ dst){
  int bid = blockIdx.x;
  int m = bid >> 6;                       // 0..5
  int off = ((bid & 63) << 8) + threadIdx.x;
  float v;
  if (m < 4){
    int r = off >> 7, ch = off & 127;
    int a = ((m & 1) << 6) + (r >> 1);
    const float* src = (m < 2) ? ((r & 1) ? s_lg : s_l) : ((r & 1) ? s_rg : s_r);
    v = src[(a << 7) + ch];
  } else if (m == 4) v = s_o[off];
  else v = s_ow[off];
  dst[(m << 14) + off] = f2b(v);
}

// ---------------- kernel 1a: LayerNorm streamer -> xn_g[j][i][ch] bf16 ----------------
__global__ __launch_bounds__(256) void ln_k(
    const float* __restrict__ x, const float* __restrict__ nw, const float* __restrict__ nb,
    u16* __restrict__ xng)
{
  const int tid = threadIdx.x, lane = tid & 63, wid = tid >> 6;
  const int bid = blockIdx.x;
  const int c = bid % NN, r0 = (bid / NN) * 64;
  const int l15 = lane & 15, lg = lane >> 4;

  float4 w0 = *(const float4*)(nw + l15*8);
  float4 w1 = *(const float4*)(nw + l15*8 + 4);
  float4 bb0 = *(const float4*)(nb + l15*8);
  float4 bb1 = *(const float4*)(nb + l15*8 + 4);
  float4 v0[4], v1[4];
  #pragma unroll
  for (int it = 0; it < 4; ++it){
    int p = wid*16 + it*4 + lg;
    const float* xp = x + ((size_t)(r0 + p)*NN + c)*DIMC + l15*8;
    v0[it] = *(const float4*)xp;
    v1[it] = *(const float4*)(xp + 4);
  }
  #pragma unroll
  for (int it = 0; it < 4; ++it){
    int p = wid*16 + it*4 + lg;
    float s  = (v0[it].x+v0[it].y)+(v0[it].z+v0[it].w)+((v1[it].x+v1[it].y)+(v1[it].z+v1[it].w));
    float sq = v0[it].x*v0[it].x+v0[it].y*v0[it].y+v0[it].z*v0[it].z+v0[it].w*v0[it].w
             + v1[it].x*v1[it].x+v1[it].y*v1[it].y+v1[it].z*v1[it].z+v1[it].w*v1[it].w;
    #pragma unroll
    for (int o = 8; o; o >>= 1){ s += __shfl_xor(s, o); sq += __shfl_xor(sq, o); }
    float mean = s * (1.0f/128.0f);
    float var  = sq * (1.0f/128.0f) - mean*mean;
    float inv  = rsqrtf(var + EPSV);
    bf16x8 o8;
    o8[0] = (short)f2b((v0[it].x - mean)*inv*w0.x + bb0.x);
    o8[1] = (short)f2b((v0[it].y - mean)*inv*w0.y + bb0.y);
    o8[2] = (short)f2b((v0[it].z - mean)*inv*w0.z + bb0.z);
    o8[3] = (short)f2b((v0[it].w - mean)*inv*w0.w + bb0.w);
    o8[4] = (short)f2b((v1[it].x - mean)*inv*w1.x + bb1.x);
    o8[5] = (short)f2b((v1[it].y - mean)*inv*w1.y + bb1.y);
    o8[6] = (short)f2b((v1[it].z - mean)*inv*w1.z + bb1.z);
    o8[7] = (short)f2b((v1[it].w - mean)*inv*w1.w + bb1.w);
    *(bf16x8*)(xng + ((size_t)c*NN + r0 + p)*DIMC + l15*8) = o8;
  }
}

// ---------------- kernel 1b: projection GEMM, 128x128 tiles, K=128 single-stage ----------------
// grid 5760 = 8 XCD x 720 (bijective). nt = n-tile (1152), t = m-tile (5).
// A = weight tile, B = xn rows, both LDS via XOR-swizzled glds16. 4 waves, 64x64 each.
// t<4: acc r = (V_q, G_q, V_{q+1}, G_{q+1}) -> fused sigmoid, direct stores.
// t=4: ogate -> sigmoid -> LDS transpose with pi(e) = (e&15)*8 + (e>>4) -> gate[i][j][pi(e)].
__global__ __launch_bounds__(256) void projB_k(const u16* __restrict__ xng, const u16* __restrict__ wb2,
    const float* __restrict__ left_b, const float* __restrict__ lgate_b,
    const float* __restrict__ right_b, const float* __restrict__ rgate_b,
    const float* __restrict__ ogate_b,
    u16* __restrict__ Lp, u16* __restrict__ Rp, u16* __restrict__ gate)
{
  __shared__ u16 lds[32768];          // 65536 B: A [0,16384), B [16384,32768)
  u16* Asl = lds;
  u16* Bsl = lds + 16384;
  const int tid = threadIdx.x, lane = tid & 63, wid = tid >> 6;
  const int bid = blockIdx.x;
  const int xcd = bid & 7, idx = bid >> 3;
  const int g = xcd*720 + idx;
  const int nt = g / 5, t = g % 5;
  const int c = nt / 3, r0 = (nt % 3) * 128;
  const size_t posbase = (size_t)c*NN + r0;
  const int l15 = lane & 15, lg = lane >> 4;
  const int wm = wid >> 1, wn = wid & 1;

  const u16* Aw = wb2 + t*16384;
  const u16* Bx = xng + posbase*DIMC;
  #pragma unroll
  for (int it = 0; it < 8; ++it){
    int cidx = it*256 + tid;
    int row = cidx >> 4, sl = cidx & 15;
    int so = row*128 + ((sl ^ (row & 15)) * 8);
    glds16(Aw + so, Asl + cidx*8);
    glds16(Bx + so, Bsl + cidx*8);
  }
  asm volatile("s_waitcnt vmcnt(0)" ::: "memory");
  __syncthreads();

  f32x4 acc[4][4];
  #pragma unroll
  for (int m = 0; m < 4; ++m)
    #pragma unroll
    for (int n = 0; n < 4; ++n) acc[m][n] = {0.f,0.f,0.f,0.f};

  #pragma unroll
  for (int ks = 0; ks < 4; ++ks){
    int sl = ((ks*4 + lg) ^ l15) * 8;
    bf16x8 af[4], bfr[4];
    #pragma unroll
    for (int m = 0; m < 4; ++m)
      af[m] = *(const bf16x8*)(Asl + (wm*64 + m*16 + l15)*128 + sl);
    #pragma unroll
    for (int n = 0; n < 4; ++n)
      bfr[n] = *(const bf16x8*)(Bsl + (wn*64 + n*16 + l15)*128 + sl);
    #pragma unroll
    for (int m = 0; m < 4; ++m)
      #pragma unroll
      for (int n = 0; n < 4; ++n)
        acc[m][n] = __builtin_amdgcn_mfma_f32_16x16x32_bf16(af[m], bfr[n], acc[m][n], 0, 0, 0);
  }

  if (t < 4){
    u16* dst = (t < 2) ? Lp : Rp;
    const float* bV = (t < 2) ? left_b : right_b;
    const float* bG = (t < 2) ? lgate_b : rgate_b;
    const int th = t & 1;
    #pragma unroll
    for (int m = 0; m < 4; ++m){
      int e0 = th*64 + wm*32 + m*8 + lg*2;
      float2 bv2 = *(const float2*)(bV + e0);
      float2 bg2 = *(const float2*)(bG + e0);
      #pragma unroll
      for (int n = 0; n < 4; ++n){
        size_t pp = posbase + wn*64 + n*16 + l15;
        float o0 = (acc[m][n][0] + bv2.x) * sigm(acc[m][n][1] + bg2.x);
        float o1 = (acc[m][n][2] + bv2.y) * sigm(acc[m][n][3] + bg2.y);
        dst[(size_t)e0*NPOS + pp]     = f2b(o0);
        dst[(size_t)(e0+1)*NPOS + pp] = f2b(o1);
      }
    }
  } else {
    __syncthreads();   // reuse lds as [128 pos][136] transpose buf
    // column permutation: e = wm*64 + m*16 + lg*4 + r  ->  pi(e) = (lg*4+r)*8 + wm*4 + m
    #pragma unroll
    for (int m = 0; m < 4; ++m){
      int e = wm*64 + m*16 + lg*4;
      float4 bo4 = *(const float4*)(ogate_b + e);
      int colbase = (lg*4)*8 + wm*4 + m;
      #pragma unroll
      for (int n = 0; n < 4; ++n){
        int pl = wn*64 + n*16 + l15;
        lds[pl*136 + colbase     ] = f2b(sigm(acc[m][n][0] + bo4.x));
        lds[pl*136 + colbase +  8] = f2b(sigm(acc[m][n][1] + bo4.y));
        lds[pl*136 + colbase + 16] = f2b(sigm(acc[m][n][2] + bo4.z));
        lds[pl*136 + colbase + 24] = f2b(sigm(acc[m][n][3] + bo4.w));
      }
    }
    __syncthreads();
    #pragma unroll
    for (int it = 0; it < 8; ++it){
      int cidx = it*256 + tid;
      int row = cidx >> 4, s = cidx & 15;
      *(bf16x8*)(gate + ((size_t)(r0 + row)*NN + c)*DIMC + s*8) = *(const bf16x8*)(lds + row*136 + s*8);
    }
  }
}

// ---------------- kernel 2: triangle einsum -> outp[i][d][j] ----------------
__global__ __launch_bounds__(256) void phase2_k(const u16* __restrict__ Rp, const u16* __restrict__ Lp,
                                                u16* __restrict__ outp){
  __shared__ u16 lds[17408];
  u16* At = lds;
  u16* Bt = lds + 8192;
  const int tid = threadIdx.x, lane = tid & 63, wid = tid >> 6;
  const int bid = blockIdx.x;
  const int xcd = bid & 7, kk = bid >> 3;
  const int d = xcd*16 + kk/9, tile = kk % 9;
  const int i0 = (tile/3)*128, j0 = (tile%3)*128;
  const int wm = wid >> 1, wn = wid & 1;
  const int iw = wm*64, jw = wn*64;
  const int l15 = lane & 15, lg = lane >> 4;
  const int rmask = l15 & 7;

  int srcoff[4];
  #pragma unroll
  for (int cc = 0; cc < 4; ++cc){
    int idx = wid*256 + cc*64 + lane;
    int row = idx >> 3, slot = idx & 7;
    srcoff[cc] = row*NN + ((slot ^ (row & 7)) * 8);
  }

  f32x4 acc[4][4];
  #pragma unroll
  for (int m = 0; m < 4; ++m)
    #pragma unroll
    for (int n = 0; n < 4; ++n) acc[m][n] = {0.f,0.f,0.f,0.f};

  const u16* Rt0 = Rp + (size_t)d*NPOS + (size_t)i0*NN;
  const u16* Lt0 = Lp + (size_t)d*NPOS + (size_t)j0*NN;

  for (int k0 = 0; k0 < NN; k0 += 64){
    __syncthreads();
    #pragma unroll
    for (int cc = 0; cc < 4; ++cc){
      glds16(Rt0 + k0 + srcoff[cc], At + (wid*4 + cc)*512);
      glds16(Lt0 + k0 + srcoff[cc], Bt + (wid*4 + cc)*512);
    }
    asm volatile("s_waitcnt vmcnt(0)" ::: "memory");
    __syncthreads();
    #pragma unroll
    for (int ks = 0; ks < 2; ++ks){
      int sl = ((ks*4 + lg) ^ rmask) * 8;
      bf16x8 af[4], bfr[4];
      #pragma unroll
      for (int m = 0; m < 4; ++m)
        af[m] = *(const bf16x8*)(At + (iw + m*16 + l15)*64 + sl);
      #pragma unroll
      for (int n = 0; n < 4; ++n)
        bfr[n] = *(const bf16x8*)(Bt + (jw + n*16 + l15)*64 + sl);
      #pragma unroll
      for (int m = 0; m < 4; ++m)
        #pragma unroll
        for (int n = 0; n < 4; ++n)
          acc[m][n] = __builtin_amdgcn_mfma_f32_16x16x32_bf16(af[m], bfr[n], acc[m][n], 0, 0, 0);
    }
  }

  __syncthreads();
  #pragma unroll
  for (int m = 0; m < 4; ++m)
    #pragma unroll
    for (int n = 0; n < 4; ++n)
      #pragma unroll
      for (int r = 0; r < 4; ++r)
        lds[(iw + m*16 + lg*4 + r)*136 + jw + n*16 + l15] = f2b(acc[m][n][r]);
  __syncthreads();
  #pragma unroll
  for (int it = 0; it < 8; ++it){
    int idx = tid + it*256;
    int il = idx >> 4, s = idx & 15;
    *(bf16x8*)(outp + ((size_t)(i0 + il)*DIMC + d)*NN + j0 + s*8) = *(const bf16x8*)(lds + il*136 + s*8);
  }
}

// ---------------- kernel 3: LN + out-projection + gate (vectorized outp loads) ----------------
__global__ __launch_bounds__(256) void phase3_k(const u16* __restrict__ outp,
    const float* __restrict__ tonw, const float* __restrict__ tonb,
    const u16* __restrict__ wOut, const float* __restrict__ out_b,
    const u16* __restrict__ gate, float* __restrict__ out)
{
  __shared__ __align__(16) char shbuf[64*132*2];   // sred[32][64]+sqred[32][64] then xn2[64][132]
  float (*sred)[64]  = (float(*)[64])shbuf;
  float (*sqred)[64] = (float(*)[64])(shbuf + 8192);
  u16* xn2 = (u16*)shbuf;
  __shared__ float marr[64], iarr[64];
  const int tid = threadIdx.x, lane = tid & 63, wid = tid >> 6;
  const int bid = blockIdx.x;
  const int i = bid % NN, j0 = (bid / NN) * 64;
  const int l15 = lane & 15, lg = lane >> 4;

  const int jg = tid & 7;
  const int hg = tid >> 3;        // 0..31
  const int hb = hg * 4;
  const u16* lbase = outp + ((size_t)i*DIMC + hb)*NN + j0 + jg*8;
  bf16x8 v8[4];
  #pragma unroll
  for (int q = 0; q < 4; ++q) v8[q] = *(const bf16x8*)(lbase + (size_t)q*NN);

  float ps[8], psq[8];
  #pragma unroll
  for (int k = 0; k < 8; ++k){ ps[k] = 0.f; psq[k] = 0.f; }
  #pragma unroll
  for (int q = 0; q < 4; ++q)
    #pragma unroll
    for (int k = 0; k < 8; ++k){
      float v = b2f((u16)v8[q][k]);
      ps[k] += v; psq[k] += v*v;
    }
  {
    float4 a = {ps[0],ps[1],ps[2],ps[3]}, b = {ps[4],ps[5],ps[6],ps[7]};
    float4 c = {psq[0],psq[1],psq[2],psq[3]}, d = {psq[4],psq[5],psq[6],psq[7]};
    *(float4*)&sred[hg][jg*8]      = a;
    *(float4*)&sred[hg][jg*8 + 4]  = b;
    *(float4*)&sqred[hg][jg*8]     = c;
    *(float4*)&sqred[hg][jg*8 + 4] = d;
  }
  __syncthreads();
  if (tid < 64){
    float ts = 0.f, tq = 0.f;
    #pragma unroll
    for (int g2 = 0; g2 < 32; ++g2){ ts += sred[g2][tid]; tq += sqred[g2][tid]; }
    float mn  = ts * (1.f/128.f);
    float var = tq * (1.f/128.f) - mn*mn;
    marr[tid] = mn; iarr[tid] = rsqrtf(var + EPSV);
  }
  __syncthreads();

  {
    float mm[8], ii[8];
    #pragma unroll
    for (int k = 0; k < 8; ++k){ mm[k] = marr[jg*8 + k]; ii[k] = iarr[jg*8 + k]; }
    float4 tw = *(const float4*)(tonw + hb);
    float4 tb = *(const float4*)(tonb + hb);
    #pragma unroll
    for (int q = 0; q < 4; ++q){
      float w = q==0?tw.x : q==1?tw.y : q==2?tw.z : tw.w;
      float b = q==0?tb.x : q==1?tb.y : q==2?tb.z : tb.w;
      int h = hb + q;
      #pragma unroll
      for (int k = 0; k < 8; ++k){
        float v = b2f((u16)v8[q][k]);
        xn2[(jg*8 + k)*132 + h] = f2b((v - mm[k])*ii[k]*w + b);
      }
    }
  }
  __syncthreads();

  f32x4 acc[8];
  #pragma unroll
  for (int n = 0; n < 8; ++n) acc[n] = {0.f,0.f,0.f,0.f};
  const int row = wid*16 + l15;
  const int kofs = lg * 8;
  #pragma unroll
  for (int ks = 0; ks < 4; ++ks){
    const u16* ap = xn2 + row*132 + ks*32 + kofs;
    bf16x4 a0 = *(const bf16x4*)ap;
    bf16x4 a1 = *(const bf16x4*)(ap + 4);
    bf16x8 af = __builtin_shufflevector(a0, a1, 0,1,2,3,4,5,6,7);
    #pragma unroll
    for (int n = 0; n < 8; ++n){
      bf16x8 bm = *(const bf16x8*)(wOut + (n*16 + l15)*128 + ks*32 + kofs);
      acc[n] = __builtin_amdgcn_mfma_f32_16x16x32_bf16(af, bm, acc[n], 0, 0, 0);
    }
  }
  #pragma unroll
  for (int r = 0; r < 4; ++r){
    int p = wid*16 + lg*4 + r;
    bf16x8 g8 = *(const bf16x8*)(gate + ((size_t)i*NN + j0 + p)*DIMC + l15*8);
    #pragma unroll
    for (int n = 0; n < 8; ++n){
      int dd = n*16 + l15;
      size_t base = ((size_t)i*NN + j0 + p)*DIMC + dd;
      out[base] = (acc[n][r] + out_b[dd]) * b2f((u16)g8[n]);
    }
  }
}

extern "C" void kernel_launch(void* const* d_in, const int* in_sizes, int n_in,
                              void* d_out, int out_size, void* d_ws, size_t ws_size,
                              hipStream_t stream){
  const float* x       = (const float*)d_in[0];
  const float* norm_w  = (const float*)d_in[1];
  const float* norm_b  = (const float*)d_in[2];
  const float* left_w  = (const float*)d_in[3];
  const float* left_b  = (const float*)d_in[4];
  const float* right_w = (const float*)d_in[5];
  const float* right_b = (const float*)d_in[6];
  const float* lgate_w = (const float*)d_in[7];
  const float* lgate_b = (const float*)d_in[8];
  const float* rgate_w = (const float*)d_in[9];
  const float* rgate_b = (const float*)d_in[10];
  const float* ogate_w = (const float*)d_in[11];
  const float* ogate_b = (const float*)d_in[12];
  const float* ton_w   = (const float*)d_in[13];
  const float* ton_b   = (const float*)d_in[14];
  const float* out_w   = (const float*)d_in[15];
  const float* out_b   = (const float*)d_in[16];

  char* ws = (char*)d_ws;
  const size_t SZ = (size_t)NPOS * DIMC * sizeof(u16);
  u16* Lp   = (u16*)(ws);
  u16* Rp   = (u16*)(ws + SZ);
  u16* gate = (u16*)(ws + 2*SZ);
  u16* outp = (u16*)(ws + 3*SZ);
  u16* wb   = (u16*)(ws + 4*SZ);
  u16* xng  = outp;   // xn_g aliases outp: fully consumed by projB before phase2 writes outp

  wconv_k<<<dim3(384), dim3(256), 0, stream>>>(left_w, lgate_w, right_w, rgate_w, ogate_w, out_w, wb);
  ln_k<<<dim3(2304), dim3(256), 0, stream>>>(x, norm_w, norm_b, xng);
  projB_k<<<dim3(5760), dim3(256), 0, stream>>>(xng, wb,
      left_b, lgate_b, right_b, rgate_b, ogate_b, Lp, Rp, gate);
  phase2_k<<<dim3(1152), dim3(256), 0, stream>>>(Rp, Lp, outp);
  phase3_k<<<dim3(2304), dim3(256), 0, stream>>>(outp, ton_w, ton_b, wb + 5*16384, out_b, gate, (float*)d_out);
}